// Round 15
// baseline (1222.023 us; speedup 1.0000x reference)
//
#include <hip/hip_runtime.h>
#include <math.h>

typedef _Float16 h2f __attribute__((ext_vector_type(2)));

__device__ __forceinline__ float fdot2f(h2f a, h2f b, float c) {
#if __has_builtin(__builtin_amdgcn_fdot2)
  return __builtin_amdgcn_fdot2(a, b, c, false);
#else
  return c + (float)a[0] * (float)b[0] + (float)a[1] * (float)b[1];
#endif
}

// DPP quad_perm cross-lane (VALU pipe): 0xB1 -> lane^1, 0x4E -> lane^2.
template <int CTRL>
__device__ __forceinline__ float dpp_f(float x) {
  union { float f; int i; } u, r;
  u.f = x;
  r.i = __builtin_amdgcn_update_dpp(0, u.i, CTRL, 0xF, 0xF, false);
  return r.f;
}

__device__ __forceinline__ float sigf(float x) {
  return __builtin_amdgcn_rcpf(1.f + __expf(-x));
}
__device__ __forceinline__ float tanh_fast(float x) {
  return 2.f * __builtin_amdgcn_rcpf(1.f + __expf(-2.f * x)) - 1.f;
}

__device__ __forceinline__ int clampi(int v, int lo, int hi) {
  return v < lo ? lo : (v > hi ? hi : v);
}

// ---------------------------------------------------------------------------
// Kernel A: per-token: ft gather + char conv (3,4,5) -> lstm_in[1024][450]
// ---------------------------------------------------------------------------
__global__ __launch_bounds__(64) void k_token(
    const float* __restrict__ fast_text, const float* __restrict__ char_table,
    const float* __restrict__ w3, const float* __restrict__ b3,
    const float* __restrict__ w4, const float* __restrict__ b4,
    const float* __restrict__ w5, const float* __restrict__ b5,
    const int* __restrict__ word_ids, const int* __restrict__ char_ids,
    float* __restrict__ lstm_in) {
  const int t = blockIdx.x;
  const int tid = threadIdx.x;
  __shared__ float ce[16][16];  // ce[l][ci]
  for (int i = tid; i < 256; i += 64) {
    int l = i >> 4, ci = i & 15;
    ce[l][ci] = char_table[char_ids[t * 16 + l] * 16 + ci];
  }
  __syncthreads();
  const int wid = word_ids[t];
  for (int d = tid; d < 300; d += 64)
    lstm_in[t * 450 + d] = fast_text[wid * 300 + d];
  const int f = tid;
  if (f < 50) {
    {
      float acc[14];
#pragma unroll
      for (int p = 0; p < 14; ++p) acc[p] = 0.f;
      for (int ci = 0; ci < 16; ++ci) {
#pragma unroll
        for (int kk = 0; kk < 3; ++kk) {
          float wv = w3[(f * 16 + ci) * 3 + kk];
#pragma unroll
          for (int p = 0; p < 14; ++p) acc[p] += ce[p + kk][ci] * wv;
        }
      }
      float m = acc[0];
#pragma unroll
      for (int p = 1; p < 14; ++p) m = fmaxf(m, acc[p]);
      lstm_in[t * 450 + 300 + f] = fmaxf(0.f, m + b3[f]);
    }
    {
      float acc[13];
#pragma unroll
      for (int p = 0; p < 13; ++p) acc[p] = 0.f;
      for (int ci = 0; ci < 16; ++ci) {
#pragma unroll
        for (int kk = 0; kk < 4; ++kk) {
          float wv = w4[(f * 16 + ci) * 4 + kk];
#pragma unroll
          for (int p = 0; p < 13; ++p) acc[p] += ce[p + kk][ci] * wv;
        }
      }
      float m = acc[0];
#pragma unroll
      for (int p = 1; p < 13; ++p) m = fmaxf(m, acc[p]);
      lstm_in[t * 450 + 350 + f] = fmaxf(0.f, m + b4[f]);
    }
    {
      float acc[12];
#pragma unroll
      for (int p = 0; p < 12; ++p) acc[p] = 0.f;
      for (int ci = 0; ci < 16; ++ci) {
#pragma unroll
        for (int kk = 0; kk < 5; ++kk) {
          float wv = w5[(f * 16 + ci) * 5 + kk];
#pragma unroll
          for (int p = 0; p < 12; ++p) acc[p] += ce[p + kk][ci] * wv;
        }
      }
      float m = acc[0];
#pragma unroll
      for (int p = 1; p < 12; ++p) m = fmaxf(m, acc[p]);
      lstm_in[t * 450 + 400 + f] = fmaxf(0.f, m + b5[f]);
    }
  }
}

// ---------------------------------------------------------------------------
// Generic fp32 GEMM: C[M][N] = A[M][K] @ W[N][K]^T (+ bias[N] if non-null)
// ---------------------------------------------------------------------------
__global__ __launch_bounds__(256) void gemm_nt(
    const float* __restrict__ A, const float* __restrict__ W,
    const float* __restrict__ bias, float* __restrict__ C,
    int M, int N, int K) {
  __shared__ float As[16][64];
  __shared__ float Ws[16][64];
  const int tid = threadIdx.x;
  const int tx = tid & 15, ty = tid >> 4;
  const int r0 = blockIdx.x * 64, c0 = blockIdx.y * 64;
  float acc[4][4] = {};
  for (int k0 = 0; k0 < K; k0 += 16) {
    for (int i = tid; i < 1024; i += 256) {
      int rr = i >> 4, kk = i & 15;
      int r = r0 + rr, k = k0 + kk;
      As[kk][rr] = (r < M && k < K) ? A[r * K + k] : 0.f;
      int c = c0 + rr;
      Ws[kk][rr] = (c < N && k < K) ? W[c * K + k] : 0.f;
    }
    __syncthreads();
#pragma unroll
    for (int kk = 0; kk < 16; ++kk) {
      const float4 av = *(const float4*)(&As[kk][ty * 4]);
      const float4 wv = *(const float4*)(&Ws[kk][tx * 4]);
      float a[4] = {av.x, av.y, av.z, av.w};
      float w[4] = {wv.x, wv.y, wv.z, wv.w};
#pragma unroll
      for (int i = 0; i < 4; ++i)
#pragma unroll
        for (int j = 0; j < 4; ++j) acc[i][j] += a[i] * w[j];
    }
    __syncthreads();
  }
#pragma unroll
  for (int i = 0; i < 4; ++i) {
    int r = r0 + ty * 4 + i;
    if (r >= M) continue;
#pragma unroll
    for (int j = 0; j < 4; ++j) {
      int c = c0 + tx * 4 + j;
      if (c < N) C[r * N + c] = acc[i][j] + (bias ? bias[c] : 0.f);
    }
  }
}

// ---------------------------------------------------------------------------
// Fused xproj GEMM: both directions in one launch.
// ---------------------------------------------------------------------------
__global__ __launch_bounds__(256) void gemm_xproj(
    const float* __restrict__ A,
    const float* __restrict__ Wf, const float* __restrict__ bf,
    const float* __restrict__ Wb, const float* __restrict__ bb,
    float* __restrict__ xpF, float* __restrict__ xpB) {
  const int M = 1024, N = 600, K = 450;
  const bool back = blockIdx.y >= 10;
  const float* __restrict__ W = back ? Wb : Wf;
  const float* __restrict__ bias = back ? bb : bf;
  float* __restrict__ C = back ? xpB : xpF;
  const int yb = back ? (blockIdx.y - 10) : blockIdx.y;

  __shared__ float As[16][64];
  __shared__ float Ws[16][64];
  const int tid = threadIdx.x;
  const int tx = tid & 15, ty = tid >> 4;
  const int r0 = blockIdx.x * 64, c0 = yb * 64;
  float acc[4][4] = {};
  for (int k0 = 0; k0 < K; k0 += 16) {
    for (int i = tid; i < 1024; i += 256) {
      int rr = i >> 4, kk = i & 15;
      int r = r0 + rr, k = k0 + kk;
      As[kk][rr] = (r < M && k < K) ? A[r * K + k] : 0.f;
      int c = c0 + rr;
      Ws[kk][rr] = (c < N && k < K) ? W[c * K + k] : 0.f;
    }
    __syncthreads();
#pragma unroll
    for (int kk = 0; kk < 16; ++kk) {
      const float4 av = *(const float4*)(&As[kk][ty * 4]);
      const float4 wv = *(const float4*)(&Ws[kk][tx * 4]);
      float a[4] = {av.x, av.y, av.z, av.w};
      float w[4] = {wv.x, wv.y, wv.z, wv.w};
#pragma unroll
      for (int i = 0; i < 4; ++i)
#pragma unroll
        for (int j = 0; j < 4; ++j) acc[i][j] += a[i] * w[j];
    }
    __syncthreads();
  }
#pragma unroll
  for (int i = 0; i < 4; ++i) {
    int r = r0 + ty * 4 + i;
#pragma unroll
    for (int j = 0; j < 4; ++j) {
      int c = c0 + tx * 4 + j;
      if (c < N) C[r * N + c] = acc[i][j] + bias[c];
    }
  }
}

// ---------------------------------------------------------------------------
// Kernel C: LSTM recurrence, one block per direction. r15 structure:
// 256 threads (4 waves, grant ~256 regs per the r10/r14 ledger). Thread
// (g = tid&3, b = tid>>2) computes partials of rows 10b..10b+9 over
// k-quarter g: 10x20 = 200 weight h2f regs, and ONLY 5 ds_read_b128 per
// step, all issued up-front into named float4s (the r14 lesson: 19 reads
// with 0 spare regs = ~2200 cy serialized-latency chain; 5 pipelined reads
// = one ~170 cy exposure). 10 independent fdot2 chains (400 cy issue),
// DPP quad-reduce per row, branchy constant-index writes (rule-#20-safe)
// into zsh[r][b] (row 10b+r), gate phase via 4 precomputed byte offsets.
// ---------------------------------------------------------------------------
__global__ __launch_bounds__(256, 1) void k_lstm(
    const float* __restrict__ xprojF, const float* __restrict__ xprojB,
    const float* __restrict__ Wh_f, const float* __restrict__ Wh_b,
    float* __restrict__ keys) {
  const int dir = blockIdx.x;
  const float* __restrict__ xp = dir ? xprojB : xprojF;
  const float* __restrict__ Wh = dir ? Wh_b : Wh_f;
  const int tid = threadIdx.x;
  const int g = tid & 3;   // k-quarter
  const int b = tid >> 2;  // quad id 0..63 (rows 10b..10b+9; >=600 unused)

  __shared__ alignas(16) h2f hbuf[2][80];  // h packed f16: 150 + 10 zero pad
  __shared__ float zsh[10][64];            // z for row 10b+r at zsh[r][b]

  // weights: 10 rows x 20 h2f covering halfs [40g, 40g+40)
  h2f w0[20], w1[20], w2[20], w3[20], w4[20];
  h2f w5[20], w6[20], w7[20], w8[20], w9[20];
#define LOADROW(WARR, R)                                              \
  {                                                                   \
    const int row_ = 10 * b + (R);                                    \
    const float* Rp_ = Wh + (row_ < 600 ? row_ : 599) * 150;          \
    _Pragma("unroll") for (int kk = 0; kk < 20; ++kk) {               \
      const int k_ = 40 * g + 2 * kk;                                 \
      float x0_ = 0.f, x1_ = 0.f;                                     \
      if (k_ < 150) {                                                 \
        float2 p_ = *(const float2*)(Rp_ + k_);                       \
        x0_ = p_.x;                                                   \
        x1_ = p_.y;                                                   \
      }                                                               \
      h2f v_;                                                         \
      v_[0] = (_Float16)x0_;                                          \
      v_[1] = (_Float16)x1_;                                          \
      WARR[kk] = v_;                                                  \
    }                                                                 \
  }
  LOADROW(w0, 0) LOADROW(w1, 1) LOADROW(w2, 2) LOADROW(w3, 3) LOADROW(w4, 4)
  LOADROW(w5, 5) LOADROW(w6, 6) LOADROW(w7, 7) LOADROW(w8, 8) LOADROW(w9, 9)
#undef LOADROW

  for (int i = tid; i < 160; i += 256) {
    h2f z;
    z[0] = (_Float16)0.f;
    z[1] = (_Float16)0.f;
    hbuf[i / 80][i % 80] = z;
  }

  // write rows of this thread (stride-4 within its 10): g, g+4, g+8
  const int wr0 = clampi(10 * b + g, 0, 599);
  const int wr1 = clampi(10 * b + g + 4, 0, 599);
  const int wr2 = clampi(10 * b + g + 8, 0, 599);

  // gate-phase byte offsets (unit u = tid < 150): rows u+150i -> zsh[r][b]
  int go0 = 0, go1 = 0, go2 = 0, go3 = 0;
  if (tid < 150) {
    const int r0_ = tid, r1_ = tid + 150, r2_ = tid + 300, r3_ = tid + 450;
    go0 = (r0_ % 10) * 64 + r0_ / 10;
    go1 = (r1_ % 10) * 64 + r1_ / 10;
    go2 = (r2_ % 10) * 64 + r2_ / 10;
    go3 = (r3_ % 10) * 64 + r3_ / 10;
  }

  float c = 0.f;
  const int t0 = dir ? 1023 : 0;
  float xv0 = xp[t0 * 600 + wr0];
  float xv1 = xp[t0 * 600 + wr1];
  float xv2 = xp[t0 * 600 + wr2];
  __syncthreads();

  int cur = 0;
  for (int step = 0; step < 1024; ++step) {
    const int t = dir ? (1023 - step) : step;
    const int tn = dir ? (t > 0 ? t - 1 : 0) : (t < 1023 ? t + 1 : 1023);
    // prefetch next step's xp (consumed after the dot chain)
    const float xn0 = xp[tn * 600 + wr0];
    const float xn1 = xp[tn * 600 + wr1];
    const float xn2 = xp[tn * 600 + wr2];
    // stage this thread's h quarter: 5 b128 broadcast reads, all in flight
    const float4* hv = (const float4*)hbuf[cur] + 5 * g;
    float4 q0 = hv[0], q1 = hv[1], q2 = hv[2], q3 = hv[3], q4 = hv[4];
    float a[10];
#pragma unroll
    for (int r = 0; r < 10; ++r) a[r] = 0.f;
#define DOTC(Q, KB)                                                   \
  {                                                                   \
    const h2f* hh_ = (const h2f*)&Q;                                  \
    _Pragma("unroll") for (int m = 0; m < 4; ++m) {                   \
      const h2f hk_ = hh_[m];                                         \
      a[0] = fdot2f(w0[(KB) + m], hk_, a[0]);                         \
      a[1] = fdot2f(w1[(KB) + m], hk_, a[1]);                         \
      a[2] = fdot2f(w2[(KB) + m], hk_, a[2]);                         \
      a[3] = fdot2f(w3[(KB) + m], hk_, a[3]);                         \
      a[4] = fdot2f(w4[(KB) + m], hk_, a[4]);                         \
      a[5] = fdot2f(w5[(KB) + m], hk_, a[5]);                         \
      a[6] = fdot2f(w6[(KB) + m], hk_, a[6]);                         \
      a[7] = fdot2f(w7[(KB) + m], hk_, a[7]);                         \
      a[8] = fdot2f(w8[(KB) + m], hk_, a[8]);                         \
      a[9] = fdot2f(w9[(KB) + m], hk_, a[9]);                         \
    }                                                                 \
  }
    DOTC(q0, 0) DOTC(q1, 4) DOTC(q2, 8) DOTC(q3, 12) DOTC(q4, 16)
#undef DOTC
    // quad reduce: every lane ends with the full row sums
#pragma unroll
    for (int r = 0; r < 10; ++r) {
      const float e = a[r] + dpp_f<0xB1>(a[r]);
      a[r] = e + dpp_f<0x4E>(e);
    }
    // constant-index writes (rule #20): branch on uniform g
    if (g == 0) {
      zsh[0][b] = a[0] + xv0;
      zsh[4][b] = a[4] + xv1;
      zsh[8][b] = a[8] + xv2;
    } else if (g == 1) {
      zsh[1][b] = a[1] + xv0;
      zsh[5][b] = a[5] + xv1;
      zsh[9][b] = a[9] + xv2;
    } else if (g == 2) {
      zsh[2][b] = a[2] + xv0;
      zsh[6][b] = a[6] + xv1;
    } else {
      zsh[3][b] = a[3] + xv0;
      zsh[7][b] = a[7] + xv1;
    }
    xv0 = xn0;
    xv1 = xn1;
    xv2 = xn2;
    __syncthreads();
    // gate phase: thread u owns hidden unit u
    if (tid < 150) {
      const float* zf_ = (const float*)zsh;
      const float zi = zf_[go0];
      const float zf = zf_[go1];
      const float zg = zf_[go2];
      const float zo = zf_[go3];
      const float ig = sigf(zi);
      const float fg = sigf(zf);
      const float gg = tanh_fast(zg);
      const float og = sigf(zo);
      c = fg * c + ig * gg;
      const float h = og * tanh_fast(c);
      keys[t * 300 + dir * 150 + tid] = h;
      ((_Float16*)hbuf[cur ^ 1])[tid] = (_Float16)h;
    }
    cur ^= 1;
    __syncthreads();
  }
}

// ---------------------------------------------------------------------------
// Kernel D: span scorer -> enc[512][1000]
// ---------------------------------------------------------------------------
__global__ __launch_bounds__(320) void k_span(
    const float* __restrict__ keys, const float* __restrict__ lstm_in,
    const float* __restrict__ W1, const float* __restrict__ b1,
    const float* __restrict__ W2, const float* __restrict__ b2,
    const float* __restrict__ w_out, const float* __restrict__ feat_table,
    const int* __restrict__ espans, float* __restrict__ enc) {
  const int e = blockIdx.x;
  const int tid = threadIdx.x;
  const int s = espans[e * 4 + 0];
  const int en = espans[e * 4 + 1];
  const int f0 = espans[e * 4 + 2];
  const int f1 = espans[e * 4 + 3];

  __shared__ float ksh[10][300];
  __shared__ float hsh[10][152];
  __shared__ float h2sh[10][152];
  __shared__ float att[10];
  __shared__ float scl[2];

  for (int i = tid; i < 3000; i += 320) {
    int p = i / 300, d = i % 300;
    int row = clampi(s + p, 0, 1023);
    ksh[p][d] = keys[row * 300 + d];
  }
  __syncthreads();

  if (tid < 152) {
    int jj = tid;
    if (jj < 150) {
      float acc[10];
#pragma unroll
      for (int p = 0; p < 10; ++p) acc[p] = b1[jj];
      for (int k = 0; k < 300; k += 4) {
        float w0 = W1[(k + 0) * 150 + jj];
        float w1 = W1[(k + 1) * 150 + jj];
        float w2 = W1[(k + 2) * 150 + jj];
        float w3 = W1[(k + 3) * 150 + jj];
#pragma unroll
        for (int p = 0; p < 10; ++p) {
          const float4 kv = *(const float4*)(&ksh[p][k]);
          acc[p] += kv.x * w0 + kv.y * w1 + kv.z * w2 + kv.w * w3;
        }
      }
#pragma unroll
      for (int p = 0; p < 10; ++p) hsh[p][jj] = fmaxf(acc[p], 0.f);
    } else {
#pragma unroll
      for (int p = 0; p < 10; ++p) hsh[p][jj] = 0.f;
    }
  }
  __syncthreads();

  if (tid < 150) {
    int jj = tid;
    float acc[10];
#pragma unroll
    for (int p = 0; p < 10; ++p) acc[p] = b2[jj];
    for (int k = 0; k < 152; k += 4) {
      float w0 = (k + 0 < 150) ? W2[(k + 0) * 150 + jj] : 0.f;
      float w1 = (k + 1 < 150) ? W2[(k + 1) * 150 + jj] : 0.f;
      float w2 = (k + 2 < 150) ? W2[(k + 2) * 150 + jj] : 0.f;
      float w3 = (k + 3 < 150) ? W2[(k + 3) * 150 + jj] : 0.f;
#pragma unroll
      for (int p = 0; p < 10; ++p) {
        const float4 hv = *(const float4*)(&hsh[p][k]);
        acc[p] += hv.x * w0 + hv.y * w1 + hv.z * w2 + hv.w * w3;
      }
    }
#pragma unroll
    for (int p = 0; p < 10; ++p) h2sh[p][jj] = fmaxf(acc[p], 0.f);
  }
  __syncthreads();

  if (tid < 10) {
    float lg = -1e30f;
    if (tid < en - s) {
      float d = 0.f;
      for (int k = 0; k < 150; ++k) d += h2sh[tid][k] * w_out[k];
      lg = d;
    }
    att[tid] = lg;
  }
  if (tid >= 64 && tid < 66) {
    int r = tid - 64;
    int fi = (r == 0) ? f0 : f1;
    float nsq = 0.f;
    for (int k = 0; k < 50; ++k) {
      float v = feat_table[fi * 50 + k];
      nsq += v * v;
    }
    float n = sqrtf(nsq);
    scl[r] = fminf(1.f, 1.f / fmaxf(n, 1e-7f));
  }
  __syncthreads();

  if (tid == 0) {
    float m = -1e30f;
    for (int p = 0; p < 10; ++p) m = fmaxf(m, att[p]);
    float ex[10];
    float ssum = 0.f;
    for (int p = 0; p < 10; ++p) {
      ex[p] = expf(att[p] - m);
      ssum += ex[p];
    }
    for (int p = 0; p < 10; ++p) att[p] = ex[p] / ssum;
  }
  __syncthreads();

  if (tid < 300) {
    int d = tid;
    float xf = keys[s * 300 + d];
    float xl = keys[(en - 1) * 300 + d];
    float xh = 0.f;
#pragma unroll
    for (int p = 0; p < 10; ++p) {
      int row = clampi(s + p, 0, 1023);
      xh += att[p] * lstm_in[row * 450 + d];
    }
    enc[e * 1000 + d] = xf;
    enc[e * 1000 + 300 + d] = xl;
    enc[e * 1000 + 600 + d] = xh;
  }
  if (tid < 100) {
    int r = tid / 50, cc = tid % 50;
    int fi = (r == 0) ? f0 : f1;
    enc[e * 1000 + 900 + tid] = feat_table[fi * 50 + cc] * scl[r];
  }
}

// ---------------------------------------------------------------------------
// Kernel E: small = enc @ affine_W + affine_b   (4 spans per block)
// ---------------------------------------------------------------------------
__global__ __launch_bounds__(320) void k_affine(
    const float* __restrict__ enc, const float* __restrict__ W,
    const float* __restrict__ bias, float* __restrict__ small) {
  const int e0 = blockIdx.x * 4;
  const int tid = threadIdx.x;
  __shared__ float es[4][1000];
  for (int i = tid; i < 4000; i += 320) es[i / 1000][i % 1000] = enc[e0 * 1000 + i];
  __syncthreads();
  if (tid < 300) {
    float a0 = bias[tid], a1 = bias[tid], a2 = bias[tid], a3 = bias[tid];
    for (int k = 0; k < 1000; k += 4) {
      float w0 = W[(k + 0) * 300 + tid];
      float w1 = W[(k + 1) * 300 + tid];
      float w2 = W[(k + 2) * 300 + tid];
      float w3 = W[(k + 3) * 300 + tid];
      const float4 v0 = *(const float4*)(&es[0][k]);
      const float4 v1 = *(const float4*)(&es[1][k]);
      const float4 v2 = *(const float4*)(&es[2][k]);
      const float4 v3 = *(const float4*)(&es[3][k]);
      a0 += v0.x * w0 + v0.y * w1 + v0.z * w2 + v0.w * w3;
      a1 += v1.x * w0 + v1.y * w1 + v1.z * w2 + v1.w * w3;
      a2 += v2.x * w0 + v2.y * w1 + v2.z * w2 + v2.w * w3;
      a3 += v3.x * w0 + v3.y * w1 + v3.z * w2 + v3.w * w3;
    }
    small[(e0 + 0) * 300 + tid] = a0;
    small[(e0 + 1) * 300 + tid] = a1;
    small[(e0 + 2) * 300 + tid] = a2;
    small[(e0 + 3) * 300 + tid] = a3;
  }
}

// ---------------------------------------------------------------------------
__global__ __launch_bounds__(64) void k_renorm(
    const float* __restrict__ actors, float* __restrict__ actorsN) {
  const int a = blockIdx.x;
  const int l = threadIdx.x;
  float nsq = 0.f;
  for (int d = l; d < 300; d += 64) {
    float v = actors[a * 300 + d];
    nsq += v * v;
  }
  for (int off = 32; off; off >>= 1) nsq += __shfl_down(nsq, off);
  nsq = __shfl(nsq, 0);
  float sc = fminf(1.f, 1.f / fmaxf(sqrtf(nsq), 1e-7f));
  for (int d = l; d < 300; d += 64) actorsN[a * 300 + d] = actors[a * 300 + d] * sc;
}

// ---------------------------------------------------------------------------
__global__ __launch_bounds__(64) void k_lse(
    const float* __restrict__ link, float* __restrict__ out) {
  const int a = blockIdx.x;
  const int l = threadIdx.x;
  float v[8];
  float m = -1e30f;
#pragma unroll
  for (int i = 0; i < 8; ++i) {
    v[i] = link[a * 512 + l + i * 64];
    m = fmaxf(m, v[i]);
  }
  for (int off = 32; off; off >>= 1) m = fmaxf(m, __shfl_xor(m, off));
  float ssum = 0.f;
#pragma unroll
  for (int i = 0; i < 8; ++i) ssum += expf(v[i] - m);
  for (int off = 32; off; off >>= 1) ssum += __shfl_xor(ssum, off);
  if (l == 0) out[a] = logf(ssum) + m;
}

// ---------------------------------------------------------------------------
extern "C" void kernel_launch(void* const* d_in, const int* in_sizes, int n_in,
                              void* d_out, int out_size, void* d_ws, size_t ws_size,
                              hipStream_t stream) {
  const float* fast_text = (const float*)d_in[0];
  const float* actor_matrix = (const float*)d_in[1];
  const float* char_table = (const float*)d_in[2];
  const float* w3 = (const float*)d_in[3];
  const float* b3 = (const float*)d_in[4];
  const float* w4 = (const float*)d_in[5];
  const float* b4 = (const float*)d_in[6];
  const float* w5 = (const float*)d_in[7];
  const float* b5 = (const float*)d_in[8];
  const float* Wi_f = (const float*)d_in[9];
  const float* Wh_f = (const float*)d_in[10];
  const float* b_f = (const float*)d_in[11];
  const float* Wi_b = (const float*)d_in[12];
  const float* Wh_b = (const float*)d_in[13];
  const float* b_b = (const float*)d_in[14];
  const float* alpha_W1 = (const float*)d_in[15];
  const float* alpha_b1 = (const float*)d_in[16];
  const float* alpha_W2 = (const float*)d_in[17];
  const float* alpha_b2 = (const float*)d_in[18];
  const float* alpha_w_out = (const float*)d_in[19];
  const float* feat_table = (const float*)d_in[20];
  const float* affine_W = (const float*)d_in[21];
  const float* affine_b = (const float*)d_in[22];
  const int* word_ids = (const int*)d_in[23];
  const int* char_ids = (const int*)d_in[24];
  const int* espans = (const int*)d_in[25];

  float* ws = (float*)d_ws;
  float* lstm_in = ws;                 // 1024*450
  float* xpF = lstm_in + 460800;       // 1024*600
  float* xpB = xpF + 614400;           // 1024*600
  float* keys = xpB + 614400;          // 1024*300
  float* enc = keys + 307200;          // 512*1000
  float* small = enc + 512000;         // 512*300
  float* actN = small + 153600;        // 2000*300

  float* out = (float*)d_out;
  float* score_link = out + 2000;  // 2000 x 512

  k_token<<<1024, 64, 0, stream>>>(fast_text, char_table, w3, b3, w4, b4, w5, b5,
                                   word_ids, char_ids, lstm_in);
  gemm_xproj<<<dim3(16, 20), 256, 0, stream>>>(lstm_in, Wi_f, b_f, Wi_b, b_b,
                                               xpF, xpB);
  k_lstm<<<2, 256, 0, stream>>>(xpF, xpB, Wh_f, Wh_b, keys);
  k_renorm<<<2000, 64, 0, stream>>>(actor_matrix, actN);
  k_span<<<512, 320, 0, stream>>>(keys, lstm_in, alpha_W1, alpha_b1, alpha_W2,
                                  alpha_b2, alpha_w_out, feat_table, espans, enc);
  k_affine<<<128, 320, 0, stream>>>(enc, affine_W, affine_b, small);
  gemm_nt<<<dim3(32, 8), 256, 0, stream>>>(actN, small, nullptr, score_link,
                                           2000, 512, 300);
  k_lse<<<2000, 64, 0, stream>>>(score_link, out);
}

// Round 16
// 1067.406 us; speedup vs baseline: 1.1449x; 1.1449x over previous
//
#include <hip/hip_runtime.h>
#include <math.h>

typedef _Float16 h2f __attribute__((ext_vector_type(2)));

__device__ __forceinline__ float fdot2f(h2f a, h2f b, float c) {
#if __has_builtin(__builtin_amdgcn_fdot2)
  return __builtin_amdgcn_fdot2(a, b, c, false);
#else
  return c + (float)a[0] * (float)b[0] + (float)a[1] * (float)b[1];
#endif
}

// DPP quad_perm cross-lane (VALU pipe): 0xB1 -> lane^1, 0x4E -> lane^2.
template <int CTRL>
__device__ __forceinline__ float dpp_f(float x) {
  union { float f; int i; } u, r;
  u.f = x;
  r.i = __builtin_amdgcn_update_dpp(0, u.i, CTRL, 0xF, 0xF, false);
  return r.f;
}

__device__ __forceinline__ float sigf(float x) {
  return __builtin_amdgcn_rcpf(1.f + __expf(-x));
}
__device__ __forceinline__ float tanh_fast(float x) {
  return 2.f * __builtin_amdgcn_rcpf(1.f + __expf(-2.f * x)) - 1.f;
}

__device__ __forceinline__ int clampi(int v, int lo, int hi) {
  return v < lo ? lo : (v > hi ? hi : v);
}

// ---------------------------------------------------------------------------
// Kernel A: per-token: ft gather + char conv (3,4,5) -> lstm_in[1024][450]
// ---------------------------------------------------------------------------
__global__ __launch_bounds__(64) void k_token(
    const float* __restrict__ fast_text, const float* __restrict__ char_table,
    const float* __restrict__ w3, const float* __restrict__ b3,
    const float* __restrict__ w4, const float* __restrict__ b4,
    const float* __restrict__ w5, const float* __restrict__ b5,
    const int* __restrict__ word_ids, const int* __restrict__ char_ids,
    float* __restrict__ lstm_in) {
  const int t = blockIdx.x;
  const int tid = threadIdx.x;
  __shared__ float ce[16][16];  // ce[l][ci]
  for (int i = tid; i < 256; i += 64) {
    int l = i >> 4, ci = i & 15;
    ce[l][ci] = char_table[char_ids[t * 16 + l] * 16 + ci];
  }
  __syncthreads();
  const int wid = word_ids[t];
  for (int d = tid; d < 300; d += 64)
    lstm_in[t * 450 + d] = fast_text[wid * 300 + d];
  const int f = tid;
  if (f < 50) {
    {
      float acc[14];
#pragma unroll
      for (int p = 0; p < 14; ++p) acc[p] = 0.f;
      for (int ci = 0; ci < 16; ++ci) {
#pragma unroll
        for (int kk = 0; kk < 3; ++kk) {
          float wv = w3[(f * 16 + ci) * 3 + kk];
#pragma unroll
          for (int p = 0; p < 14; ++p) acc[p] += ce[p + kk][ci] * wv;
        }
      }
      float m = acc[0];
#pragma unroll
      for (int p = 1; p < 14; ++p) m = fmaxf(m, acc[p]);
      lstm_in[t * 450 + 300 + f] = fmaxf(0.f, m + b3[f]);
    }
    {
      float acc[13];
#pragma unroll
      for (int p = 0; p < 13; ++p) acc[p] = 0.f;
      for (int ci = 0; ci < 16; ++ci) {
#pragma unroll
        for (int kk = 0; kk < 4; ++kk) {
          float wv = w4[(f * 16 + ci) * 4 + kk];
#pragma unroll
          for (int p = 0; p < 13; ++p) acc[p] += ce[p + kk][ci] * wv;
        }
      }
      float m = acc[0];
#pragma unroll
      for (int p = 1; p < 13; ++p) m = fmaxf(m, acc[p]);
      lstm_in[t * 450 + 350 + f] = fmaxf(0.f, m + b4[f]);
    }
    {
      float acc[12];
#pragma unroll
      for (int p = 0; p < 12; ++p) acc[p] = 0.f;
      for (int ci = 0; ci < 16; ++ci) {
#pragma unroll
        for (int kk = 0; kk < 5; ++kk) {
          float wv = w5[(f * 16 + ci) * 5 + kk];
#pragma unroll
          for (int p = 0; p < 12; ++p) acc[p] += ce[p + kk][ci] * wv;
        }
      }
      float m = acc[0];
#pragma unroll
      for (int p = 1; p < 12; ++p) m = fmaxf(m, acc[p]);
      lstm_in[t * 450 + 400 + f] = fmaxf(0.f, m + b5[f]);
    }
  }
}

// ---------------------------------------------------------------------------
// Generic fp32 GEMM: C[M][N] = A[M][K] @ W[N][K]^T (+ bias[N] if non-null)
// float4 staging loads (fast path when k+3 < K; scalar tail otherwise).
// ---------------------------------------------------------------------------
__global__ __launch_bounds__(256) void gemm_nt(
    const float* __restrict__ A, const float* __restrict__ W,
    const float* __restrict__ bias, float* __restrict__ C,
    int M, int N, int K) {
  __shared__ float As[16][64];
  __shared__ float Ws[16][64];
  const int tid = threadIdx.x;
  const int tx = tid & 15, ty = tid >> 4;
  const int r0 = blockIdx.x * 64, c0 = blockIdx.y * 64;
  const int lr = tid >> 2;        // staged row 0..63
  const int lk = (tid & 3) * 4;   // staged k-offset 0,4,8,12
  float acc[4][4] = {};
  for (int k0 = 0; k0 < K; k0 += 16) {
    {
      const int r = r0 + lr, k = k0 + lk;
      float4 av = {0.f, 0.f, 0.f, 0.f};
      if (r < M) {
        if (k + 3 < K) {
          av = *(const float4*)(&A[r * K + k]);
        } else {
          if (k + 0 < K) av.x = A[r * K + k + 0];
          if (k + 1 < K) av.y = A[r * K + k + 1];
          if (k + 2 < K) av.z = A[r * K + k + 2];
          if (k + 3 < K) av.w = A[r * K + k + 3];
        }
      }
      As[lk + 0][lr] = av.x;
      As[lk + 1][lr] = av.y;
      As[lk + 2][lr] = av.z;
      As[lk + 3][lr] = av.w;
      const int c = c0 + lr;
      float4 wv = {0.f, 0.f, 0.f, 0.f};
      if (c < N) {
        if (k + 3 < K) {
          wv = *(const float4*)(&W[c * K + k]);
        } else {
          if (k + 0 < K) wv.x = W[c * K + k + 0];
          if (k + 1 < K) wv.y = W[c * K + k + 1];
          if (k + 2 < K) wv.z = W[c * K + k + 2];
          if (k + 3 < K) wv.w = W[c * K + k + 3];
        }
      }
      Ws[lk + 0][lr] = wv.x;
      Ws[lk + 1][lr] = wv.y;
      Ws[lk + 2][lr] = wv.z;
      Ws[lk + 3][lr] = wv.w;
    }
    __syncthreads();
#pragma unroll
    for (int kk = 0; kk < 16; ++kk) {
      const float4 av = *(const float4*)(&As[kk][ty * 4]);
      const float4 wv = *(const float4*)(&Ws[kk][tx * 4]);
      float a[4] = {av.x, av.y, av.z, av.w};
      float w[4] = {wv.x, wv.y, wv.z, wv.w};
#pragma unroll
      for (int i = 0; i < 4; ++i)
#pragma unroll
        for (int j = 0; j < 4; ++j) acc[i][j] += a[i] * w[j];
    }
    __syncthreads();
  }
#pragma unroll
  for (int i = 0; i < 4; ++i) {
    int r = r0 + ty * 4 + i;
    if (r >= M) continue;
#pragma unroll
    for (int j = 0; j < 4; ++j) {
      int c = c0 + tx * 4 + j;
      if (c < N) C[r * N + c] = acc[i][j] + (bias ? bias[c] : 0.f);
    }
  }
}

// ---------------------------------------------------------------------------
// Fused xproj GEMM: both directions in one launch. float4 staging loads.
// ---------------------------------------------------------------------------
__global__ __launch_bounds__(256) void gemm_xproj(
    const float* __restrict__ A,
    const float* __restrict__ Wf, const float* __restrict__ bf,
    const float* __restrict__ Wb, const float* __restrict__ bb,
    float* __restrict__ xpF, float* __restrict__ xpB) {
  const int N = 600, K = 450;
  const bool back = blockIdx.y >= 10;
  const float* __restrict__ W = back ? Wb : Wf;
  const float* __restrict__ bias = back ? bb : bf;
  float* __restrict__ C = back ? xpB : xpF;
  const int yb = back ? (blockIdx.y - 10) : blockIdx.y;

  __shared__ float As[16][64];
  __shared__ float Ws[16][64];
  const int tid = threadIdx.x;
  const int tx = tid & 15, ty = tid >> 4;
  const int r0 = blockIdx.x * 64, c0 = yb * 64;
  const int lr = tid >> 2;
  const int lk = (tid & 3) * 4;
  float acc[4][4] = {};
  for (int k0 = 0; k0 < K; k0 += 16) {
    {
      const int r = r0 + lr, k = k0 + lk;  // r < 1024 always (grid 16x64)
      float4 av = {0.f, 0.f, 0.f, 0.f};
      if (k + 3 < K) {
        av = *(const float4*)(&A[r * K + k]);
      } else {
        if (k + 0 < K) av.x = A[r * K + k + 0];
        if (k + 1 < K) av.y = A[r * K + k + 1];
        if (k + 2 < K) av.z = A[r * K + k + 2];
        if (k + 3 < K) av.w = A[r * K + k + 3];
      }
      As[lk + 0][lr] = av.x;
      As[lk + 1][lr] = av.y;
      As[lk + 2][lr] = av.z;
      As[lk + 3][lr] = av.w;
      const int c = c0 + lr;
      float4 wv = {0.f, 0.f, 0.f, 0.f};
      if (c < N) {
        if (k + 3 < K) {
          wv = *(const float4*)(&W[c * K + k]);
        } else {
          if (k + 0 < K) wv.x = W[c * K + k + 0];
          if (k + 1 < K) wv.y = W[c * K + k + 1];
          if (k + 2 < K) wv.z = W[c * K + k + 2];
          if (k + 3 < K) wv.w = W[c * K + k + 3];
        }
      }
      Ws[lk + 0][lr] = wv.x;
      Ws[lk + 1][lr] = wv.y;
      Ws[lk + 2][lr] = wv.z;
      Ws[lk + 3][lr] = wv.w;
    }
    __syncthreads();
#pragma unroll
    for (int kk = 0; kk < 16; ++kk) {
      const float4 av = *(const float4*)(&As[kk][ty * 4]);
      const float4 wv = *(const float4*)(&Ws[kk][tx * 4]);
      float a[4] = {av.x, av.y, av.z, av.w};
      float w[4] = {wv.x, wv.y, wv.z, wv.w};
#pragma unroll
      for (int i = 0; i < 4; ++i)
#pragma unroll
        for (int j = 0; j < 4; ++j) acc[i][j] += a[i] * w[j];
    }
    __syncthreads();
  }
#pragma unroll
  for (int i = 0; i < 4; ++i) {
    int r = r0 + ty * 4 + i;
#pragma unroll
    for (int j = 0; j < 4; ++j) {
      int c = c0 + tx * 4 + j;
      if (c < N) C[r * N + c] = acc[i][j] + bias[c];
    }
  }
}

// ---------------------------------------------------------------------------
// Kernel C: LSTM recurrence, one block per direction. Split-K4 — the r8
// configuration, the measured best of 14 variants (860us; VGPR 84 with ~16
// spill regs). Thread (u = tid>>2, g = tid&3) computes partials of all 4
// gate rows of unit u over k-quarter g (5 ds_read_b128/thread/step);
// 2-stage DPP quad reduce; gate exchange via DPP; ONE barrier per step.
// Ledger (r9-r15): no knob moves the 640-thr budget off 84; clean-register
// 256-thr variants (r14: serialized reads, r15: pipelined + zsh exchange)
// are SLOWER (936/970us) -- the wall is a per-step latency chain, not
// spill or LDS throughput. This is the plateau configuration.
// ---------------------------------------------------------------------------
__global__ __launch_bounds__(640, 1) void k_lstm(
    const float* __restrict__ xprojF, const float* __restrict__ xprojB,
    const float* __restrict__ Wh_f, const float* __restrict__ Wh_b,
    float* __restrict__ keys) {
  const int dir = blockIdx.x;
  const float* __restrict__ xp = dir ? xprojB : xprojF;
  const float* __restrict__ Wh = dir ? Wh_b : Wh_f;
  const int tid = threadIdx.x;
  const int u = tid >> 2;                  // hidden unit (active < 150)
  const int g = tid & 3;                   // k-quarter / final gate row
  const int uu = u < 150 ? u : 149;        // clamped for safe addressing
  const int row = g * 150 + uu;
  const bool act = (tid < 600);

  __shared__ alignas(16) h2f hbuf[2][80];  // h packed f16: 150 + 10 zero pad

  // weights: 4 gate rows x 20 h2f covering halfs [40g, 40g+40)
  h2f w0[20], w1[20], w2[20], w3[20];
  {
    const float* R0 = Wh + (0 * 150 + uu) * 150;
    const float* R1 = Wh + (1 * 150 + uu) * 150;
    const float* R2 = Wh + (2 * 150 + uu) * 150;
    const float* R3 = Wh + (3 * 150 + uu) * 150;
#pragma unroll
    for (int kk = 0; kk < 20; ++kk) {
      const int k = 40 * g + 2 * kk;
      float a0 = 0.f, a1 = 0.f, b0 = 0.f, b1 = 0.f;
      float c0 = 0.f, c1 = 0.f, d0 = 0.f, d1 = 0.f;
      if (k < 150) {  // k even -> k+1 <= 149 also valid
        float2 p;
        p = *(const float2*)(R0 + k); a0 = p.x; a1 = p.y;
        p = *(const float2*)(R1 + k); b0 = p.x; b1 = p.y;
        p = *(const float2*)(R2 + k); c0 = p.x; c1 = p.y;
        p = *(const float2*)(R3 + k); d0 = p.x; d1 = p.y;
      }
      h2f v;
      v[0] = (_Float16)a0; v[1] = (_Float16)a1; w0[kk] = v;
      v[0] = (_Float16)b0; v[1] = (_Float16)b1; w1[kk] = v;
      v[0] = (_Float16)c0; v[1] = (_Float16)c1; w2[kk] = v;
      v[0] = (_Float16)d0; v[1] = (_Float16)d1; w3[kk] = v;
    }
  }
  for (int i = tid; i < 160; i += 640) {
    h2f z;
    z[0] = (_Float16)0.f;
    z[1] = (_Float16)0.f;
    hbuf[i / 80][i % 80] = z;
  }
  float c = 0.f;
  float xv = xp[(dir ? 1023 : 0) * 600 + row];
  __syncthreads();

  int cur = 0;
  for (int step = 0; step < 1024; ++step) {
    const int t = dir ? (1023 - step) : step;
    const int tn = dir ? (t > 0 ? t - 1 : 0) : (t < 1023 ? t + 1 : 1023);
    // prefetch next step's xp (hidden under the dot chain)
    const float xv_next = xp[tn * 600 + row];
    // 5 ds_read_b128 of this thread's k-quarter (4 broadcast groups/wave)
    const float4* hv = (const float4*)hbuf[cur] + 5 * g;
    float a0 = 0.f, a1 = 0.f, a2 = 0.f, a3 = 0.f;
#pragma unroll
    for (int i = 0; i < 5; ++i) {
      float4 q = hv[i];
      const h2f* hh = (const h2f*)&q;
#pragma unroll
      for (int m = 0; m < 4; ++m) {
        a0 = fdot2f(w0[4 * i + m], hh[m], a0);
        a1 = fdot2f(w1[4 * i + m], hh[m], a1);
        a2 = fdot2f(w2[4 * i + m], hh[m], a2);
        a3 = fdot2f(w3[4 * i + m], hh[m], a3);
      }
    }
    // stage 1: sum quarters {g, g^1} for each row
    const float e0 = a0 + dpp_f<0xB1>(a0);
    const float e1 = a1 + dpp_f<0xB1>(a1);
    const float e2 = a2 + dpp_f<0xB1>(a2);
    const float e3 = a3 + dpp_f<0xB1>(a3);
    const float fa = (g & 1) ? e1 : e0;
    const float fb = (g & 1) ? e3 : e2;
    // stage 2: sum quarters {g^2, g^3}
    const float ga_ = fa + dpp_f<0x4E>(fa);
    const float gb_ = fb + dpp_f<0x4E>(fb);
    const float z = ((g & 2) ? gb_ : ga_) + xv;
    xv = xv_next;
    // nonlinearity: sigmoid for i,f,o; tanh for g
    const float zz = (g == 2) ? 2.f * z : z;
    const float s = sigf(zz);
    const float val = (g == 2) ? (2.f * s - 1.f) : s;
    // gate exchange within the quad (DPP)
    const float v1 = dpp_f<0xB1>(val);  // at g0: f
    const float gv = dpp_f<0x4E>(val);  // at g0: g
    const float ov = dpp_f<0x4E>(v1);   // at g0: o
    if (act && g == 0) {
      c = v1 * c + val * gv;
      const float h = ov * tanh_fast(c);
      keys[t * 300 + dir * 150 + u] = h;
      ((_Float16*)hbuf[cur ^ 1])[u] = (_Float16)h;
    }
    cur ^= 1;
    __syncthreads();
  }
}

// ---------------------------------------------------------------------------
// Kernel D: span scorer -> enc[512][1000]
// ---------------------------------------------------------------------------
__global__ __launch_bounds__(320) void k_span(
    const float* __restrict__ keys, const float* __restrict__ lstm_in,
    const float* __restrict__ W1, const float* __restrict__ b1,
    const float* __restrict__ W2, const float* __restrict__ b2,
    const float* __restrict__ w_out, const float* __restrict__ feat_table,
    const int* __restrict__ espans, float* __restrict__ enc) {
  const int e = blockIdx.x;
  const int tid = threadIdx.x;
  const int s = espans[e * 4 + 0];
  const int en = espans[e * 4 + 1];
  const int f0 = espans[e * 4 + 2];
  const int f1 = espans[e * 4 + 3];

  __shared__ float ksh[10][300];
  __shared__ float hsh[10][152];
  __shared__ float h2sh[10][152];
  __shared__ float att[10];
  __shared__ float scl[2];

  for (int i = tid; i < 3000; i += 320) {
    int p = i / 300, d = i % 300;
    int row = clampi(s + p, 0, 1023);
    ksh[p][d] = keys[row * 300 + d];
  }
  __syncthreads();

  if (tid < 152) {
    int jj = tid;
    if (jj < 150) {
      float acc[10];
#pragma unroll
      for (int p = 0; p < 10; ++p) acc[p] = b1[jj];
      for (int k = 0; k < 300; k += 4) {
        float w0 = W1[(k + 0) * 150 + jj];
        float w1 = W1[(k + 1) * 150 + jj];
        float w2 = W1[(k + 2) * 150 + jj];
        float w3 = W1[(k + 3) * 150 + jj];
#pragma unroll
        for (int p = 0; p < 10; ++p) {
          const float4 kv = *(const float4*)(&ksh[p][k]);
          acc[p] += kv.x * w0 + kv.y * w1 + kv.z * w2 + kv.w * w3;
        }
      }
#pragma unroll
      for (int p = 0; p < 10; ++p) hsh[p][jj] = fmaxf(acc[p], 0.f);
    } else {
#pragma unroll
      for (int p = 0; p < 10; ++p) hsh[p][jj] = 0.f;
    }
  }
  __syncthreads();

  if (tid < 150) {
    int jj = tid;
    float acc[10];
#pragma unroll
    for (int p = 0; p < 10; ++p) acc[p] = b2[jj];
    for (int k = 0; k < 152; k += 4) {
      float w0 = (k + 0 < 150) ? W2[(k + 0) * 150 + jj] : 0.f;
      float w1 = (k + 1 < 150) ? W2[(k + 1) * 150 + jj] : 0.f;
      float w2 = (k + 2 < 150) ? W2[(k + 2) * 150 + jj] : 0.f;
      float w3 = (k + 3 < 150) ? W2[(k + 3) * 150 + jj] : 0.f;
#pragma unroll
      for (int p = 0; p < 10; ++p) {
        const float4 hv = *(const float4*)(&hsh[p][k]);
        acc[p] += hv.x * w0 + hv.y * w1 + hv.z * w2 + hv.w * w3;
      }
    }
#pragma unroll
    for (int p = 0; p < 10; ++p) h2sh[p][jj] = fmaxf(acc[p], 0.f);
  }
  __syncthreads();

  if (tid < 10) {
    float lg = -1e30f;
    if (tid < en - s) {
      float d = 0.f;
      for (int k = 0; k < 150; ++k) d += h2sh[tid][k] * w_out[k];
      lg = d;
    }
    att[tid] = lg;
  }
  if (tid >= 64 && tid < 66) {
    int r = tid - 64;
    int fi = (r == 0) ? f0 : f1;
    float nsq = 0.f;
    for (int k = 0; k < 50; ++k) {
      float v = feat_table[fi * 50 + k];
      nsq += v * v;
    }
    float n = sqrtf(nsq);
    scl[r] = fminf(1.f, 1.f / fmaxf(n, 1e-7f));
  }
  __syncthreads();

  if (tid == 0) {
    float m = -1e30f;
    for (int p = 0; p < 10; ++p) m = fmaxf(m, att[p]);
    float ex[10];
    float ssum = 0.f;
    for (int p = 0; p < 10; ++p) {
      ex[p] = expf(att[p] - m);
      ssum += ex[p];
    }
    for (int p = 0; p < 10; ++p) att[p] = ex[p] / ssum;
  }
  __syncthreads();

  if (tid < 300) {
    int d = tid;
    float xf = keys[s * 300 + d];
    float xl = keys[(en - 1) * 300 + d];
    float xh = 0.f;
#pragma unroll
    for (int p = 0; p < 10; ++p) {
      int row = clampi(s + p, 0, 1023);
      xh += att[p] * lstm_in[row * 450 + d];
    }
    enc[e * 1000 + d] = xf;
    enc[e * 1000 + 300 + d] = xl;
    enc[e * 1000 + 600 + d] = xh;
  }
  if (tid < 100) {
    int r = tid / 50, cc = tid % 50;
    int fi = (r == 0) ? f0 : f1;
    enc[e * 1000 + 900 + tid] = feat_table[fi * 50 + cc] * scl[r];
  }
}

// ---------------------------------------------------------------------------
// Kernel E: small = enc @ affine_W + affine_b   (4 spans per block)
// ---------------------------------------------------------------------------
__global__ __launch_bounds__(320) void k_affine(
    const float* __restrict__ enc, const float* __restrict__ W,
    const float* __restrict__ bias, float* __restrict__ small) {
  const int e0 = blockIdx.x * 4;
  const int tid = threadIdx.x;
  __shared__ float es[4][1000];
  for (int i = tid; i < 4000; i += 320) es[i / 1000][i % 1000] = enc[e0 * 1000 + i];
  __syncthreads();
  if (tid < 300) {
    float a0 = bias[tid], a1 = bias[tid], a2 = bias[tid], a3 = bias[tid];
    for (int k = 0; k < 1000; k += 4) {
      float w0 = W[(k + 0) * 300 + tid];
      float w1 = W[(k + 1) * 300 + tid];
      float w2 = W[(k + 2) * 300 + tid];
      float w3 = W[(k + 3) * 300 + tid];
      const float4 v0 = *(const float4*)(&es[0][k]);
      const float4 v1 = *(const float4*)(&es[1][k]);
      const float4 v2 = *(const float4*)(&es[2][k]);
      const float4 v3 = *(const float4*)(&es[3][k]);
      a0 += v0.x * w0 + v0.y * w1 + v0.z * w2 + v0.w * w3;
      a1 += v1.x * w0 + v1.y * w1 + v1.z * w2 + v1.w * w3;
      a2 += v2.x * w0 + v2.y * w1 + v2.z * w2 + v2.w * w3;
      a3 += v3.x * w0 + v3.y * w1 + v3.z * w2 + v3.w * w3;
    }
    small[(e0 + 0) * 300 + tid] = a0;
    small[(e0 + 1) * 300 + tid] = a1;
    small[(e0 + 2) * 300 + tid] = a2;
    small[(e0 + 3) * 300 + tid] = a3;
  }
}

// ---------------------------------------------------------------------------
__global__ __launch_bounds__(64) void k_renorm(
    const float* __restrict__ actors, float* __restrict__ actorsN) {
  const int a = blockIdx.x;
  const int l = threadIdx.x;
  float nsq = 0.f;
  for (int d = l; d < 300; d += 64) {
    float v = actors[a * 300 + d];
    nsq += v * v;
  }
  for (int off = 32; off; off >>= 1) nsq += __shfl_down(nsq, off);
  nsq = __shfl(nsq, 0);
  float sc = fminf(1.f, 1.f / fmaxf(sqrtf(nsq), 1e-7f));
  for (int d = l; d < 300; d += 64) actorsN[a * 300 + d] = actors[a * 300 + d] * sc;
}

// ---------------------------------------------------------------------------
__global__ __launch_bounds__(64) void k_lse(
    const float* __restrict__ link, float* __restrict__ out) {
  const int a = blockIdx.x;
  const int l = threadIdx.x;
  float v[8];
  float m = -1e30f;
#pragma unroll
  for (int i = 0; i < 8; ++i) {
    v[i] = link[a * 512 + l + i * 64];
    m = fmaxf(m, v[i]);
  }
  for (int off = 32; off; off >>= 1) m = fmaxf(m, __shfl_xor(m, off));
  float ssum = 0.f;
#pragma unroll
  for (int i = 0; i < 8; ++i) ssum += expf(v[i] - m);
  for (int off = 32; off; off >>= 1) ssum += __shfl_xor(ssum, off);
  if (l == 0) out[a] = logf(ssum) + m;
}

// ---------------------------------------------------------------------------
extern "C" void kernel_launch(void* const* d_in, const int* in_sizes, int n_in,
                              void* d_out, int out_size, void* d_ws, size_t ws_size,
                              hipStream_t stream) {
  const float* fast_text = (const float*)d_in[0];
  const float* actor_matrix = (const float*)d_in[1];
  const float* char_table = (const float*)d_in[2];
  const float* w3 = (const float*)d_in[3];
  const float* b3 = (const float*)d_in[4];
  const float* w4 = (const float*)d_in[5];
  const float* b4 = (const float*)d_in[6];
  const float* w5 = (const float*)d_in[7];
  const float* b5 = (const float*)d_in[8];
  const float* Wi_f = (const float*)d_in[9];
  const float* Wh_f = (const float*)d_in[10];
  const float* b_f = (const float*)d_in[11];
  const float* Wi_b = (const float*)d_in[12];
  const float* Wh_b = (const float*)d_in[13];
  const float* b_b = (const float*)d_in[14];
  const float* alpha_W1 = (const float*)d_in[15];
  const float* alpha_b1 = (const float*)d_in[16];
  const float* alpha_W2 = (const float*)d_in[17];
  const float* alpha_b2 = (const float*)d_in[18];
  const float* alpha_w_out = (const float*)d_in[19];
  const float* feat_table = (const float*)d_in[20];
  const float* affine_W = (const float*)d_in[21];
  const float* affine_b = (const float*)d_in[22];
  const int* word_ids = (const int*)d_in[23];
  const int* char_ids = (const int*)d_in[24];
  const int* espans = (const int*)d_in[25];

  float* ws = (float*)d_ws;
  float* lstm_in = ws;                 // 1024*450
  float* xpF = lstm_in + 460800;       // 1024*600
  float* xpB = xpF + 614400;           // 1024*600
  float* keys = xpB + 614400;          // 1024*300
  float* enc = keys + 307200;          // 512*1000
  float* small = enc + 512000;         // 512*300
  float* actN = small + 153600;        // 2000*300

  float* out = (float*)d_out;
  float* score_link = out + 2000;  // 2000 x 512

  k_token<<<1024, 64, 0, stream>>>(fast_text, char_table, w3, b3, w4, b4, w5, b5,
                                   word_ids, char_ids, lstm_in);
  gemm_xproj<<<dim3(16, 20), 256, 0, stream>>>(lstm_in, Wi_f, b_f, Wi_b, b_b,
                                               xpF, xpB);
  k_lstm<<<2, 640, 0, stream>>>(xpF, xpB, Wh_f, Wh_b, keys);
  k_renorm<<<2000, 64, 0, stream>>>(actor_matrix, actN);
  k_span<<<512, 320, 0, stream>>>(keys, lstm_in, alpha_W1, alpha_b1, alpha_W2,
                                  alpha_b2, alpha_w_out, feat_table, espans, enc);
  k_affine<<<128, 320, 0, stream>>>(enc, affine_W, affine_b, small);
  gemm_nt<<<dim3(32, 8), 256, 0, stream>>>(actN, small, nullptr, score_link,
                                           2000, 512, 300);
  k_lse<<<2000, 64, 0, stream>>>(score_link, out);
}

// Round 17
// 1066.366 us; speedup vs baseline: 1.1460x; 1.0010x over previous
//
#include <hip/hip_runtime.h>
#include <math.h>

typedef _Float16 h2f __attribute__((ext_vector_type(2)));

__device__ __forceinline__ float fdot2f(h2f a, h2f b, float c) {
#if __has_builtin(__builtin_amdgcn_fdot2)
  return __builtin_amdgcn_fdot2(a, b, c, false);
#else
  return c + (float)a[0] * (float)b[0] + (float)a[1] * (float)b[1];
#endif
}

// DPP quad_perm cross-lane (VALU pipe): 0xB1 -> lane^1, 0x4E -> lane^2.
template <int CTRL>
__device__ __forceinline__ float dpp_f(float x) {
  union { float f; int i; } u, r;
  u.f = x;
  r.i = __builtin_amdgcn_update_dpp(0, u.i, CTRL, 0xF, 0xF, false);
  return r.f;
}

__device__ __forceinline__ float sigf(float x) {
  return __builtin_amdgcn_rcpf(1.f + __expf(-x));
}
__device__ __forceinline__ float tanh_fast(float x) {
  return 2.f * __builtin_amdgcn_rcpf(1.f + __expf(-2.f * x)) - 1.f;
}

__device__ __forceinline__ int clampi(int v, int lo, int hi) {
  return v < lo ? lo : (v > hi ? hi : v);
}

// ---------------------------------------------------------------------------
// Kernel A: per-token: ft gather + char conv (3,4,5) -> lstm_in[1024][450]
// ---------------------------------------------------------------------------
__global__ __launch_bounds__(64) void k_token(
    const float* __restrict__ fast_text, const float* __restrict__ char_table,
    const float* __restrict__ w3, const float* __restrict__ b3,
    const float* __restrict__ w4, const float* __restrict__ b4,
    const float* __restrict__ w5, const float* __restrict__ b5,
    const int* __restrict__ word_ids, const int* __restrict__ char_ids,
    float* __restrict__ lstm_in) {
  const int t = blockIdx.x;
  const int tid = threadIdx.x;
  __shared__ float ce[16][16];  // ce[l][ci]
  for (int i = tid; i < 256; i += 64) {
    int l = i >> 4, ci = i & 15;
    ce[l][ci] = char_table[char_ids[t * 16 + l] * 16 + ci];
  }
  __syncthreads();
  const int wid = word_ids[t];
  for (int d = tid; d < 300; d += 64)
    lstm_in[t * 450 + d] = fast_text[wid * 300 + d];
  const int f = tid;
  if (f < 50) {
    {
      float acc[14];
#pragma unroll
      for (int p = 0; p < 14; ++p) acc[p] = 0.f;
      for (int ci = 0; ci < 16; ++ci) {
#pragma unroll
        for (int kk = 0; kk < 3; ++kk) {
          float wv = w3[(f * 16 + ci) * 3 + kk];
#pragma unroll
          for (int p = 0; p < 14; ++p) acc[p] += ce[p + kk][ci] * wv;
        }
      }
      float m = acc[0];
#pragma unroll
      for (int p = 1; p < 14; ++p) m = fmaxf(m, acc[p]);
      lstm_in[t * 450 + 300 + f] = fmaxf(0.f, m + b3[f]);
    }
    {
      float acc[13];
#pragma unroll
      for (int p = 0; p < 13; ++p) acc[p] = 0.f;
      for (int ci = 0; ci < 16; ++ci) {
#pragma unroll
        for (int kk = 0; kk < 4; ++kk) {
          float wv = w4[(f * 16 + ci) * 4 + kk];
#pragma unroll
          for (int p = 0; p < 13; ++p) acc[p] += ce[p + kk][ci] * wv;
        }
      }
      float m = acc[0];
#pragma unroll
      for (int p = 1; p < 13; ++p) m = fmaxf(m, acc[p]);
      lstm_in[t * 450 + 350 + f] = fmaxf(0.f, m + b4[f]);
    }
    {
      float acc[12];
#pragma unroll
      for (int p = 0; p < 12; ++p) acc[p] = 0.f;
      for (int ci = 0; ci < 16; ++ci) {
#pragma unroll
        for (int kk = 0; kk < 5; ++kk) {
          float wv = w5[(f * 16 + ci) * 5 + kk];
#pragma unroll
          for (int p = 0; p < 12; ++p) acc[p] += ce[p + kk][ci] * wv;
        }
      }
      float m = acc[0];
#pragma unroll
      for (int p = 1; p < 12; ++p) m = fmaxf(m, acc[p]);
      lstm_in[t * 450 + 400 + f] = fmaxf(0.f, m + b5[f]);
    }
  }
}

// ---------------------------------------------------------------------------
// Generic fp32 GEMM: C[M][N] = A[M][K] @ W[N][K]^T (+ bias[N] if non-null)
// float4 staging loads (fast path when k+3 < K; scalar tail otherwise).
// ---------------------------------------------------------------------------
__global__ __launch_bounds__(256) void gemm_nt(
    const float* __restrict__ A, const float* __restrict__ W,
    const float* __restrict__ bias, float* __restrict__ C,
    int M, int N, int K) {
  __shared__ float As[16][64];
  __shared__ float Ws[16][64];
  const int tid = threadIdx.x;
  const int tx = tid & 15, ty = tid >> 4;
  const int r0 = blockIdx.x * 64, c0 = blockIdx.y * 64;
  const int lr = tid >> 2;        // staged row 0..63
  const int lk = (tid & 3) * 4;   // staged k-offset 0,4,8,12
  float acc[4][4] = {};
  for (int k0 = 0; k0 < K; k0 += 16) {
    {
      const int r = r0 + lr, k = k0 + lk;
      float4 av = {0.f, 0.f, 0.f, 0.f};
      if (r < M) {
        if (k + 3 < K) {
          av = *(const float4*)(&A[r * K + k]);
        } else {
          if (k + 0 < K) av.x = A[r * K + k + 0];
          if (k + 1 < K) av.y = A[r * K + k + 1];
          if (k + 2 < K) av.z = A[r * K + k + 2];
          if (k + 3 < K) av.w = A[r * K + k + 3];
        }
      }
      As[lk + 0][lr] = av.x;
      As[lk + 1][lr] = av.y;
      As[lk + 2][lr] = av.z;
      As[lk + 3][lr] = av.w;
      const int c = c0 + lr;
      float4 wv = {0.f, 0.f, 0.f, 0.f};
      if (c < N) {
        if (k + 3 < K) {
          wv = *(const float4*)(&W[c * K + k]);
        } else {
          if (k + 0 < K) wv.x = W[c * K + k + 0];
          if (k + 1 < K) wv.y = W[c * K + k + 1];
          if (k + 2 < K) wv.z = W[c * K + k + 2];
          if (k + 3 < K) wv.w = W[c * K + k + 3];
        }
      }
      Ws[lk + 0][lr] = wv.x;
      Ws[lk + 1][lr] = wv.y;
      Ws[lk + 2][lr] = wv.z;
      Ws[lk + 3][lr] = wv.w;
    }
    __syncthreads();
#pragma unroll
    for (int kk = 0; kk < 16; ++kk) {
      const float4 av = *(const float4*)(&As[kk][ty * 4]);
      const float4 wv = *(const float4*)(&Ws[kk][tx * 4]);
      float a[4] = {av.x, av.y, av.z, av.w};
      float w[4] = {wv.x, wv.y, wv.z, wv.w};
#pragma unroll
      for (int i = 0; i < 4; ++i)
#pragma unroll
        for (int j = 0; j < 4; ++j) acc[i][j] += a[i] * w[j];
    }
    __syncthreads();
  }
#pragma unroll
  for (int i = 0; i < 4; ++i) {
    int r = r0 + ty * 4 + i;
    if (r >= M) continue;
#pragma unroll
    for (int j = 0; j < 4; ++j) {
      int c = c0 + tx * 4 + j;
      if (c < N) C[r * N + c] = acc[i][j] + (bias ? bias[c] : 0.f);
    }
  }
}

// ---------------------------------------------------------------------------
// Fused xproj GEMM: both directions in one launch. float4 staging loads.
// ---------------------------------------------------------------------------
__global__ __launch_bounds__(256) void gemm_xproj(
    const float* __restrict__ A,
    const float* __restrict__ Wf, const float* __restrict__ bf,
    const float* __restrict__ Wb, const float* __restrict__ bb,
    float* __restrict__ xpF, float* __restrict__ xpB) {
  const int N = 600, K = 450;
  const bool back = blockIdx.y >= 10;
  const float* __restrict__ W = back ? Wb : Wf;
  const float* __restrict__ bias = back ? bb : bf;
  float* __restrict__ C = back ? xpB : xpF;
  const int yb = back ? (blockIdx.y - 10) : blockIdx.y;

  __shared__ float As[16][64];
  __shared__ float Ws[16][64];
  const int tid = threadIdx.x;
  const int tx = tid & 15, ty = tid >> 4;
  const int r0 = blockIdx.x * 64, c0 = yb * 64;
  const int lr = tid >> 2;
  const int lk = (tid & 3) * 4;
  float acc[4][4] = {};
  for (int k0 = 0; k0 < K; k0 += 16) {
    {
      const int r = r0 + lr, k = k0 + lk;  // r < 1024 always (grid 16x64)
      float4 av = {0.f, 0.f, 0.f, 0.f};
      if (k + 3 < K) {
        av = *(const float4*)(&A[r * K + k]);
      } else {
        if (k + 0 < K) av.x = A[r * K + k + 0];
        if (k + 1 < K) av.y = A[r * K + k + 1];
        if (k + 2 < K) av.z = A[r * K + k + 2];
        if (k + 3 < K) av.w = A[r * K + k + 3];
      }
      As[lk + 0][lr] = av.x;
      As[lk + 1][lr] = av.y;
      As[lk + 2][lr] = av.z;
      As[lk + 3][lr] = av.w;
      const int c = c0 + lr;
      float4 wv = {0.f, 0.f, 0.f, 0.f};
      if (c < N) {
        if (k + 3 < K) {
          wv = *(const float4*)(&W[c * K + k]);
        } else {
          if (k + 0 < K) wv.x = W[c * K + k + 0];
          if (k + 1 < K) wv.y = W[c * K + k + 1];
          if (k + 2 < K) wv.z = W[c * K + k + 2];
          if (k + 3 < K) wv.w = W[c * K + k + 3];
        }
      }
      Ws[lk + 0][lr] = wv.x;
      Ws[lk + 1][lr] = wv.y;
      Ws[lk + 2][lr] = wv.z;
      Ws[lk + 3][lr] = wv.w;
    }
    __syncthreads();
#pragma unroll
    for (int kk = 0; kk < 16; ++kk) {
      const float4 av = *(const float4*)(&As[kk][ty * 4]);
      const float4 wv = *(const float4*)(&Ws[kk][tx * 4]);
      float a[4] = {av.x, av.y, av.z, av.w};
      float w[4] = {wv.x, wv.y, wv.z, wv.w};
#pragma unroll
      for (int i = 0; i < 4; ++i)
#pragma unroll
        for (int j = 0; j < 4; ++j) acc[i][j] += a[i] * w[j];
    }
    __syncthreads();
  }
#pragma unroll
  for (int i = 0; i < 4; ++i) {
    int r = r0 + ty * 4 + i;
#pragma unroll
    for (int j = 0; j < 4; ++j) {
      int c = c0 + tx * 4 + j;
      if (c < N) C[r * N + c] = acc[i][j] + bias[c];
    }
  }
}

// ---------------------------------------------------------------------------
// Kernel C: LSTM recurrence + fused actor renorm.
// Blocks 0,1: split-K4 LSTM (r8 config, measured best of 8 variants:
//   ~880us; VGPR 84, ~16-reg spill; per-step latency chain is the floor).
// Blocks 2..201: actor renorm, one actor per wave (10 waves x 10 actors/blk)
//   -- data-independent of the LSTM chain, so these 2000 actors complete on
//   the 254 idle CUs entirely under the LSTM's 880us shadow, removing
//   k_renorm's ~20us serial slot from the timeline.
// ---------------------------------------------------------------------------
__global__ __launch_bounds__(640, 1) void k_lstm(
    const float* __restrict__ xprojF, const float* __restrict__ xprojB,
    const float* __restrict__ Wh_f, const float* __restrict__ Wh_b,
    float* __restrict__ keys,
    const float* __restrict__ actors, float* __restrict__ actorsN) {
  if (blockIdx.x >= 2) {
    // ---- renorm path: one actor per wave ----
    const int wave = threadIdx.x >> 6;
    const int lane = threadIdx.x & 63;
    const int a = (blockIdx.x - 2) * 10 + wave;
    if (a < 2000) {
      float nsq = 0.f;
      for (int d = lane; d < 300; d += 64) {
        float v = actors[a * 300 + d];
        nsq += v * v;
      }
      for (int off = 32; off; off >>= 1) nsq += __shfl_down(nsq, off);
      nsq = __shfl(nsq, 0);
      float sc = fminf(1.f, 1.f / fmaxf(sqrtf(nsq), 1e-7f));
      for (int d = lane; d < 300; d += 64)
        actorsN[a * 300 + d] = actors[a * 300 + d] * sc;
    }
    return;
  }

  const int dir = blockIdx.x;
  const float* __restrict__ xp = dir ? xprojB : xprojF;
  const float* __restrict__ Wh = dir ? Wh_b : Wh_f;
  const int tid = threadIdx.x;
  const int u = tid >> 2;                  // hidden unit (active < 150)
  const int g = tid & 3;                   // k-quarter / final gate row
  const int uu = u < 150 ? u : 149;        // clamped for safe addressing
  const int row = g * 150 + uu;
  const bool act = (tid < 600);

  __shared__ alignas(16) h2f hbuf[2][80];  // h packed f16: 150 + 10 zero pad

  // weights: 4 gate rows x 20 h2f covering halfs [40g, 40g+40)
  h2f w0[20], w1[20], w2[20], w3[20];
  {
    const float* R0 = Wh + (0 * 150 + uu) * 150;
    const float* R1 = Wh + (1 * 150 + uu) * 150;
    const float* R2 = Wh + (2 * 150 + uu) * 150;
    const float* R3 = Wh + (3 * 150 + uu) * 150;
#pragma unroll
    for (int kk = 0; kk < 20; ++kk) {
      const int k = 40 * g + 2 * kk;
      float a0 = 0.f, a1 = 0.f, b0 = 0.f, b1 = 0.f;
      float c0 = 0.f, c1 = 0.f, d0 = 0.f, d1 = 0.f;
      if (k < 150) {  // k even -> k+1 <= 149 also valid
        float2 p;
        p = *(const float2*)(R0 + k); a0 = p.x; a1 = p.y;
        p = *(const float2*)(R1 + k); b0 = p.x; b1 = p.y;
        p = *(const float2*)(R2 + k); c0 = p.x; c1 = p.y;
        p = *(const float2*)(R3 + k); d0 = p.x; d1 = p.y;
      }
      h2f v;
      v[0] = (_Float16)a0; v[1] = (_Float16)a1; w0[kk] = v;
      v[0] = (_Float16)b0; v[1] = (_Float16)b1; w1[kk] = v;
      v[0] = (_Float16)c0; v[1] = (_Float16)c1; w2[kk] = v;
      v[0] = (_Float16)d0; v[1] = (_Float16)d1; w3[kk] = v;
    }
  }
  for (int i = tid; i < 160; i += 640) {
    h2f z;
    z[0] = (_Float16)0.f;
    z[1] = (_Float16)0.f;
    hbuf[i / 80][i % 80] = z;
  }
  float c = 0.f;
  float xv = xp[(dir ? 1023 : 0) * 600 + row];
  __syncthreads();

  int cur = 0;
  for (int step = 0; step < 1024; ++step) {
    const int t = dir ? (1023 - step) : step;
    const int tn = dir ? (t > 0 ? t - 1 : 0) : (t < 1023 ? t + 1 : 1023);
    // prefetch next step's xp (hidden under the dot chain)
    const float xv_next = xp[tn * 600 + row];
    // 5 ds_read_b128 of this thread's k-quarter (4 broadcast groups/wave)
    const float4* hv = (const float4*)hbuf[cur] + 5 * g;
    float a0 = 0.f, a1 = 0.f, a2 = 0.f, a3 = 0.f;
#pragma unroll
    for (int i = 0; i < 5; ++i) {
      float4 q = hv[i];
      const h2f* hh = (const h2f*)&q;
#pragma unroll
      for (int m = 0; m < 4; ++m) {
        a0 = fdot2f(w0[4 * i + m], hh[m], a0);
        a1 = fdot2f(w1[4 * i + m], hh[m], a1);
        a2 = fdot2f(w2[4 * i + m], hh[m], a2);
        a3 = fdot2f(w3[4 * i + m], hh[m], a3);
      }
    }
    // stage 1: sum quarters {g, g^1} for each row
    const float e0 = a0 + dpp_f<0xB1>(a0);
    const float e1 = a1 + dpp_f<0xB1>(a1);
    const float e2 = a2 + dpp_f<0xB1>(a2);
    const float e3 = a3 + dpp_f<0xB1>(a3);
    const float fa = (g & 1) ? e1 : e0;
    const float fb = (g & 1) ? e3 : e2;
    // stage 2: sum quarters {g^2, g^3}
    const float ga_ = fa + dpp_f<0x4E>(fa);
    const float gb_ = fb + dpp_f<0x4E>(fb);
    const float z = ((g & 2) ? gb_ : ga_) + xv;
    xv = xv_next;
    // nonlinearity: sigmoid for i,f,o; tanh for g
    const float zz = (g == 2) ? 2.f * z : z;
    const float s = sigf(zz);
    const float val = (g == 2) ? (2.f * s - 1.f) : s;
    // gate exchange within the quad (DPP)
    const float v1 = dpp_f<0xB1>(val);  // at g0: f
    const float gv = dpp_f<0x4E>(val);  // at g0: g
    const float ov = dpp_f<0x4E>(v1);   // at g0: o
    if (act && g == 0) {
      c = v1 * c + val * gv;
      const float h = ov * tanh_fast(c);
      keys[t * 300 + dir * 150 + u] = h;
      ((_Float16*)hbuf[cur ^ 1])[u] = (_Float16)h;
    }
    cur ^= 1;
    __syncthreads();
  }
}

// ---------------------------------------------------------------------------
// Kernel D: span scorer -> enc[512][1000]
// ---------------------------------------------------------------------------
__global__ __launch_bounds__(320) void k_span(
    const float* __restrict__ keys, const float* __restrict__ lstm_in,
    const float* __restrict__ W1, const float* __restrict__ b1,
    const float* __restrict__ W2, const float* __restrict__ b2,
    const float* __restrict__ w_out, const float* __restrict__ feat_table,
    const int* __restrict__ espans, float* __restrict__ enc) {
  const int e = blockIdx.x;
  const int tid = threadIdx.x;
  const int s = espans[e * 4 + 0];
  const int en = espans[e * 4 + 1];
  const int f0 = espans[e * 4 + 2];
  const int f1 = espans[e * 4 + 3];

  __shared__ float ksh[10][300];
  __shared__ float hsh[10][152];
  __shared__ float h2sh[10][152];
  __shared__ float att[10];
  __shared__ float scl[2];

  for (int i = tid; i < 3000; i += 320) {
    int p = i / 300, d = i % 300;
    int row = clampi(s + p, 0, 1023);
    ksh[p][d] = keys[row * 300 + d];
  }
  __syncthreads();

  if (tid < 152) {
    int jj = tid;
    if (jj < 150) {
      float acc[10];
#pragma unroll
      for (int p = 0; p < 10; ++p) acc[p] = b1[jj];
      for (int k = 0; k < 300; k += 4) {
        float w0 = W1[(k + 0) * 150 + jj];
        float w1 = W1[(k + 1) * 150 + jj];
        float w2 = W1[(k + 2) * 150 + jj];
        float w3 = W1[(k + 3) * 150 + jj];
#pragma unroll
        for (int p = 0; p < 10; ++p) {
          const float4 kv = *(const float4*)(&ksh[p][k]);
          acc[p] += kv.x * w0 + kv.y * w1 + kv.z * w2 + kv.w * w3;
        }
      }
#pragma unroll
      for (int p = 0; p < 10; ++p) hsh[p][jj] = fmaxf(acc[p], 0.f);
    } else {
#pragma unroll
      for (int p = 0; p < 10; ++p) hsh[p][jj] = 0.f;
    }
  }
  __syncthreads();

  if (tid < 150) {
    int jj = tid;
    float acc[10];
#pragma unroll
    for (int p = 0; p < 10; ++p) acc[p] = b2[jj];
    for (int k = 0; k < 152; k += 4) {
      float w0 = (k + 0 < 150) ? W2[(k + 0) * 150 + jj] : 0.f;
      float w1 = (k + 1 < 150) ? W2[(k + 1) * 150 + jj] : 0.f;
      float w2 = (k + 2 < 150) ? W2[(k + 2) * 150 + jj] : 0.f;
      float w3 = (k + 3 < 150) ? W2[(k + 3) * 150 + jj] : 0.f;
#pragma unroll
      for (int p = 0; p < 10; ++p) {
        const float4 hv = *(const float4*)(&hsh[p][k]);
        acc[p] += hv.x * w0 + hv.y * w1 + hv.z * w2 + hv.w * w3;
      }
    }
#pragma unroll
    for (int p = 0; p < 10; ++p) h2sh[p][jj] = fmaxf(acc[p], 0.f);
  }
  __syncthreads();

  if (tid < 10) {
    float lg = -1e30f;
    if (tid < en - s) {
      float d = 0.f;
      for (int k = 0; k < 150; ++k) d += h2sh[tid][k] * w_out[k];
      lg = d;
    }
    att[tid] = lg;
  }
  if (tid >= 64 && tid < 66) {
    int r = tid - 64;
    int fi = (r == 0) ? f0 : f1;
    float nsq = 0.f;
    for (int k = 0; k < 50; ++k) {
      float v = feat_table[fi * 50 + k];
      nsq += v * v;
    }
    float n = sqrtf(nsq);
    scl[r] = fminf(1.f, 1.f / fmaxf(n, 1e-7f));
  }
  __syncthreads();

  if (tid == 0) {
    float m = -1e30f;
    for (int p = 0; p < 10; ++p) m = fmaxf(m, att[p]);
    float ex[10];
    float ssum = 0.f;
    for (int p = 0; p < 10; ++p) {
      ex[p] = expf(att[p] - m);
      ssum += ex[p];
    }
    for (int p = 0; p < 10; ++p) att[p] = ex[p] / ssum;
  }
  __syncthreads();

  if (tid < 300) {
    int d = tid;
    float xf = keys[s * 300 + d];
    float xl = keys[(en - 1) * 300 + d];
    float xh = 0.f;
#pragma unroll
    for (int p = 0; p < 10; ++p) {
      int row = clampi(s + p, 0, 1023);
      xh += att[p] * lstm_in[row * 450 + d];
    }
    enc[e * 1000 + d] = xf;
    enc[e * 1000 + 300 + d] = xl;
    enc[e * 1000 + 600 + d] = xh;
  }
  if (tid < 100) {
    int r = tid / 50, cc = tid % 50;
    int fi = (r == 0) ? f0 : f1;
    enc[e * 1000 + 900 + tid] = feat_table[fi * 50 + cc] * scl[r];
  }
}

// ---------------------------------------------------------------------------
// Kernel E: small = enc @ affine_W + affine_b   (4 spans per block)
// ---------------------------------------------------------------------------
__global__ __launch_bounds__(320) void k_affine(
    const float* __restrict__ enc, const float* __restrict__ W,
    const float* __restrict__ bias, float* __restrict__ small) {
  const int e0 = blockIdx.x * 4;
  const int tid = threadIdx.x;
  __shared__ float es[4][1000];
  for (int i = tid; i < 4000; i += 320) es[i / 1000][i % 1000] = enc[e0 * 1000 + i];
  __syncthreads();
  if (tid < 300) {
    float a0 = bias[tid], a1 = bias[tid], a2 = bias[tid], a3 = bias[tid];
    for (int k = 0; k < 1000; k += 4) {
      float w0 = W[(k + 0) * 300 + tid];
      float w1 = W[(k + 1) * 300 + tid];
      float w2 = W[(k + 2) * 300 + tid];
      float w3 = W[(k + 3) * 300 + tid];
      const float4 v0 = *(const float4*)(&es[0][k]);
      const float4 v1 = *(const float4*)(&es[1][k]);
      const float4 v2 = *(const float4*)(&es[2][k]);
      const float4 v3 = *(const float4*)(&es[3][k]);
      a0 += v0.x * w0 + v0.y * w1 + v0.z * w2 + v0.w * w3;
      a1 += v1.x * w0 + v1.y * w1 + v1.z * w2 + v1.w * w3;
      a2 += v2.x * w0 + v2.y * w1 + v2.z * w2 + v2.w * w3;
      a3 += v3.x * w0 + v3.y * w1 + v3.z * w2 + v3.w * w3;
    }
    small[(e0 + 0) * 300 + tid] = a0;
    small[(e0 + 1) * 300 + tid] = a1;
    small[(e0 + 2) * 300 + tid] = a2;
    small[(e0 + 3) * 300 + tid] = a3;
  }
}

// ---------------------------------------------------------------------------
__global__ __launch_bounds__(64) void k_lse(
    const float* __restrict__ link, float* __restrict__ out) {
  const int a = blockIdx.x;
  const int l = threadIdx.x;
  float v[8];
  float m = -1e30f;
#pragma unroll
  for (int i = 0; i < 8; ++i) {
    v[i] = link[a * 512 + l + i * 64];
    m = fmaxf(m, v[i]);
  }
  for (int off = 32; off; off >>= 1) m = fmaxf(m, __shfl_xor(m, off));
  float ssum = 0.f;
#pragma unroll
  for (int i = 0; i < 8; ++i) ssum += expf(v[i] - m);
  for (int off = 32; off; off >>= 1) ssum += __shfl_xor(ssum, off);
  if (l == 0) out[a] = logf(ssum) + m;
}

// ---------------------------------------------------------------------------
extern "C" void kernel_launch(void* const* d_in, const int* in_sizes, int n_in,
                              void* d_out, int out_size, void* d_ws, size_t ws_size,
                              hipStream_t stream) {
  const float* fast_text = (const float*)d_in[0];
  const float* actor_matrix = (const float*)d_in[1];
  const float* char_table = (const float*)d_in[2];
  const float* w3 = (const float*)d_in[3];
  const float* b3 = (const float*)d_in[4];
  const float* w4 = (const float*)d_in[5];
  const float* b4 = (const float*)d_in[6];
  const float* w5 = (const float*)d_in[7];
  const float* b5 = (const float*)d_in[8];
  const float* Wi_f = (const float*)d_in[9];
  const float* Wh_f = (const float*)d_in[10];
  const float* b_f = (const float*)d_in[11];
  const float* Wi_b = (const float*)d_in[12];
  const float* Wh_b = (const float*)d_in[13];
  const float* b_b = (const float*)d_in[14];
  const float* alpha_W1 = (const float*)d_in[15];
  const float* alpha_b1 = (const float*)d_in[16];
  const float* alpha_W2 = (const float*)d_in[17];
  const float* alpha_b2 = (const float*)d_in[18];
  const float* alpha_w_out = (const float*)d_in[19];
  const float* feat_table = (const float*)d_in[20];
  const float* affine_W = (const float*)d_in[21];
  const float* affine_b = (const float*)d_in[22];
  const int* word_ids = (const int*)d_in[23];
  const int* char_ids = (const int*)d_in[24];
  const int* espans = (const int*)d_in[25];

  float* ws = (float*)d_ws;
  float* lstm_in = ws;                 // 1024*450
  float* xpF = lstm_in + 460800;       // 1024*600
  float* xpB = xpF + 614400;           // 1024*600
  float* keys = xpB + 614400;          // 1024*300
  float* enc = keys + 307200;          // 512*1000
  float* small = enc + 512000;         // 512*300
  float* actN = small + 153600;        // 2000*300

  float* out = (float*)d_out;
  float* score_link = out + 2000;  // 2000 x 512

  k_token<<<1024, 64, 0, stream>>>(fast_text, char_table, w3, b3, w4, b4, w5, b5,
                                   word_ids, char_ids, lstm_in);
  gemm_xproj<<<dim3(16, 20), 256, 0, stream>>>(lstm_in, Wi_f, b_f, Wi_b, b_b,
                                               xpF, xpB);
  k_lstm<<<202, 640, 0, stream>>>(xpF, xpB, Wh_f, Wh_b, keys,
                                  actor_matrix, actN);
  k_span<<<512, 320, 0, stream>>>(keys, lstm_in, alpha_W1, alpha_b1, alpha_W2,
                                  alpha_b2, alpha_w_out, feat_table, espans, enc);
  k_affine<<<128, 320, 0, stream>>>(enc, affine_W, affine_b, small);
  gemm_nt<<<dim3(32, 8), 256, 0, stream>>>(actN, small, nullptr, score_link,
                                           2000, 512, 300);
  k_lse<<<2000, 64, 0, stream>>>(score_link, out);
}